// Round 1
// baseline (119.684 us; speedup 1.0000x reference)
//
#include <hip/hip_runtime.h>
#include <cstdint>

#define EPSF 1e-7f

// ---------------------------------------------------------------------------
// K1: per-face normal, scattered (atomicAdd) into per-vertex accumulators.
// h_state layout: (b, 6, n_v) -> x,y,z arrays contiguous per batch (SoA).
// h_faces layout: (b, 3, n_f).
// ---------------------------------------------------------------------------
__global__ void face_scatter_kernel(const float* __restrict__ hs,
                                    const int* __restrict__ hf,
                                    float* __restrict__ svec,   // (b*n_v*3) sums
                                    float* __restrict__ scnt,   // (b*n_v) counts
                                    int n_v, int n_f, int bs) {
    int t = blockIdx.x * blockDim.x + threadIdx.x;
    if (t >= bs * n_f) return;
    int b = t / n_f;
    int f = t - b * n_f;
    const int* fb = hf + (size_t)b * 3 * n_f;
    int i0 = fb[f];
    int i1 = fb[n_f + f];
    int i2 = fb[2 * n_f + f];
    const float* xs = hs + (size_t)b * 6 * n_v;
    const float* ys = xs + n_v;
    const float* zs = xs + 2 * n_v;
    float ax = xs[i0], ay = ys[i0], az = zs[i0];
    float bx = xs[i1], by = ys[i1], bz = zs[i1];
    float cx = xs[i2], cy = ys[i2], cz = zs[i2];
    float e1x = bx - ax, e1y = by - ay, e1z = bz - az;
    float e2x = cx - ax, e2y = cy - ay, e2z = cz - az;
    float fx = e1y * e2z - e1z * e2y;
    float fy = e1z * e2x - e1x * e2z;
    float fz = e1x * e2y - e1y * e2x;
    float nrm = sqrtf(fx * fx + fy * fy + fz * fz) + EPSF;
    fx /= nrm; fy /= nrm; fz /= nrm;
    float* sb = svec + (size_t)b * n_v * 3;
    float* cb = scnt + (size_t)b * n_v;
    int idx3[3] = {i0, i1, i2};
    #pragma unroll
    for (int k = 0; k < 3; ++k) {
        int i = idx3[k];
        atomicAdd(&sb[i * 3 + 0], fx);
        atomicAdd(&sb[i * 3 + 1], fy);
        atomicAdd(&sb[i * 3 + 2], fz);
        atomicAdd(&cb[i], 1.0f);
    }
}

// ---------------------------------------------------------------------------
// K2: vn = s/(c+EPS); un = vn/(||vn||+EPS).  In-place over svec.
// ---------------------------------------------------------------------------
__global__ void vertex_normal_kernel(float* __restrict__ svec,
                                     const float* __restrict__ scnt,
                                     int total) {
    int t = blockIdx.x * blockDim.x + threadIdx.x;
    if (t >= total) return;
    float cc = scnt[t] + EPSF;
    float vx = svec[t * 3 + 0] / cc;
    float vy = svec[t * 3 + 1] / cc;
    float vz = svec[t * 3 + 2] / cc;
    float nrm = sqrtf(vx * vx + vy * vy + vz * vz) + EPSF;
    svec[t * 3 + 0] = vx / nrm;
    svec[t * 3 + 1] = vy / nrm;
    svec[t * 3 + 2] = vz / nrm;
}

// ---------------------------------------------------------------------------
// K3: one wave (64 lanes) per query point. Lanes scan 64 vertices per
// iteration (coalesced SoA loads), ballot the within-radius mask, extract
// set bits in vertex-index order (= ball-query semantics), early-exit at 4
// hits. Epilogue (wave-uniform) computes the per-point squared masked-mean
// penetration; block writes a partial (double) for stage-2 reduction.
// ---------------------------------------------------------------------------
__global__ void query_loss_kernel(const float* __restrict__ pred,
                                  const float* __restrict__ hs,
                                  const float* __restrict__ un,
                                  double* __restrict__ partial,
                                  float* __restrict__ pcnt,
                                  int n_v, int n_pred, int bs) {
    const int lane = threadIdx.x & 63;
    const int wave = threadIdx.x >> 6;
    const int wid = blockIdx.x * 4 + wave;   // global wave id == query id
    const int nq = bs * n_pred;

    float per_pt = 0.0f;
    float is_pos = 0.0f;

    if (wid < nq) {
        const int b = wid / n_pred;
        const int q = wid - b * n_pred;
        const float* xs = hs + (size_t)b * 6 * n_v;
        const float* ys = xs + n_v;
        const float* zs = xs + 2 * n_v;
        const float* unb = un + (size_t)b * n_v * 3;
        const float px = pred[((size_t)b * n_pred + q) * 3 + 0];
        const float py = pred[((size_t)b * n_pred + q) * 3 + 1];
        const float pz = pred[((size_t)b * n_pred + q) * 3 + 2];

        int found = 0;
        int h0 = 0, h1 = 0, h2 = 0, h3 = 0;
        const int nchunks = (n_v + 63) >> 6;
        for (int c = 0; c < nchunks; ++c) {
            int v = (c << 6) + lane;
            int vc = v < n_v ? v : (n_v - 1);
            float dx = px - xs[vc];
            float dy = py - ys[vc];
            float dz = pz - zs[vc];
            float d2 = dx * dx + dy * dy + dz * dz;
            // 0.01f == float(0.1*0.1) as JAX computes the f32 threshold
            bool within = (v < n_v) && (d2 < 0.01f);
            unsigned long long m = __ballot(within);
            while (m != 0ull && found < 4) {
                int bit = __builtin_ctzll(m);
                int vid = (c << 6) + bit;
                if (found == 0)      h0 = vid;
                else if (found == 1) h1 = vid;
                else if (found == 2) h2 = vid;
                else                 h3 = vid;
                ++found;
                m &= m - 1;
            }
            if (found >= 4) break;
        }

        // slots: j-th hit if it exists, else first hit (0 when no hits)
        int id0 = h0;                       // h0 defaults to 0
        int id1 = (found > 1) ? h1 : h0;
        int id2 = (found > 2) ? h2 : h0;
        int id3 = (found > 3) ? h3 : h0;
        int ids[4] = {id0, id1, id2, id3};

        float vd[4];
        float cm = 0.0f;
        #pragma unroll
        for (int j = 0; j < 4; ++j) {
            int id = ids[j];
            float dx = px - xs[id];
            float dy = py - ys[id];
            float dz = pz - zs[id];
            float nx = unb[id * 3 + 0];
            float ny = unb[id * 3 + 1];
            float nz = unb[id * 3 + 2];
            float dot = dx * nx + dy * ny + dz * nz;
            float w = (dot >= -0.1f) ? 1.0f : 0.0f;
            float v = (dot - 0.001f) * w;
            bool msk = v < 0.0f;            // -0.0 < 0 is false, as in ref
            vd[j] = msk ? v : 0.0f;
            cm += msk ? 1.0f : 0.0f;
        }
        float s = ((vd[0] + vd[1]) + vd[2]) + vd[3];
        float a = s / (cm + EPSF);
        per_pt = a * a;
        is_pos = (per_pt > 0.0f) ? 1.0f : 0.0f;
    }

    __shared__ float ls[4];
    __shared__ float lc[4];
    if (lane == 0) { ls[wave] = per_pt; lc[wave] = is_pos; }
    __syncthreads();
    if (threadIdx.x == 0) {
        double ssum = (double)ls[0] + (double)ls[1] + (double)ls[2] + (double)ls[3];
        float csum = ((lc[0] + lc[1]) + lc[2]) + lc[3];
        partial[blockIdx.x] = ssum;
        pcnt[blockIdx.x] = csum;
    }
}

// ---------------------------------------------------------------------------
// K4: single-block reduction of the block partials -> final scalar loss.
// ---------------------------------------------------------------------------
__global__ void finalize_kernel(const double* __restrict__ partial,
                                const float* __restrict__ pcnt,
                                int n, float* __restrict__ out) {
    double s = 0.0, c = 0.0;
    for (int i = threadIdx.x; i < n; i += blockDim.x) {
        s += partial[i];
        c += (double)pcnt[i];
    }
    #pragma unroll
    for (int off = 32; off > 0; off >>= 1) {
        s += __shfl_down(s, off);
        c += __shfl_down(c, off);
    }
    __shared__ double ws_s[4];
    __shared__ double ws_c[4];
    int wave = threadIdx.x >> 6;
    int lane = threadIdx.x & 63;
    if (lane == 0) { ws_s[wave] = s; ws_c[wave] = c; }
    __syncthreads();
    if (threadIdx.x == 0) {
        double S = ws_s[0] + ws_s[1] + ws_s[2] + ws_s[3];
        double C = ws_c[0] + ws_c[1] + ws_c[2] + ws_c[3];
        out[0] = (float)(S / (C + 1e-7));
    }
}

extern "C" void kernel_launch(void* const* d_in, const int* in_sizes, int n_in,
                              void* d_out, int out_size, void* d_ws, size_t ws_size,
                              hipStream_t stream) {
    const float* pred    = (const float*)d_in[0];
    // d_in[1] = label, unused by the reference
    const float* h_state = (const float*)d_in[2];
    const int*   h_faces = (const int*)d_in[3];
    float* out = (float*)d_out;

    const int bs = 2;
    const int n_pred = in_sizes[0] / (bs * 3);   // 8192
    const int n_v    = in_sizes[2] / (bs * 6);   // 6890
    const int n_f    = in_sizes[3] / (bs * 3);   // 13776

    // workspace layout (floats): [svec: bs*n_v*3][scnt: bs*n_v] then doubles
    float* svec = (float*)d_ws;
    float* scnt = svec + (size_t)bs * n_v * 3;
    size_t off_f = (size_t)bs * n_v * 4;         // 55120 floats (even -> 8B ok)
    off_f = (off_f + 1) & ~(size_t)1;
    const int nq = bs * n_pred;                  // 16384
    const int nblk = (nq + 3) / 4;               // 4 waves (queries) per block
    double* partial = (double*)(svec + off_f);
    float*  pcnt    = (float*)(partial + nblk);

    // zero the scatter accumulators (ws is re-poisoned before every launch)
    hipMemsetAsync(d_ws, 0, (size_t)bs * n_v * 4 * sizeof(float), stream);

    int t1 = bs * n_f;
    face_scatter_kernel<<<(t1 + 255) / 256, 256, 0, stream>>>(
        h_state, h_faces, svec, scnt, n_v, n_f, bs);

    int t2 = bs * n_v;
    vertex_normal_kernel<<<(t2 + 255) / 256, 256, 0, stream>>>(svec, scnt, t2);

    query_loss_kernel<<<nblk, 256, 0, stream>>>(
        pred, h_state, svec, partial, pcnt, n_v, n_pred, bs);

    finalize_kernel<<<1, 256, 0, stream>>>(partial, pcnt, nblk, out);
}